// Round 14
// baseline (218.703 us; speedup 1.0000x reference)
//
#include <hip/hip_runtime.h>
#include <hip/hip_bf16.h>

// Pipeline (N=50000, E=1.6M, D=16, NK=2):
//   bhist: LDS-private bucket histogram (bucket = dst>>7, 391 buckets)
//   bscan: column-sum + scan 512 slots -> bbase/bcur(padded)/off[N]=E
//   partA: bucket-partition edges into staging (LDS-staged)
//   partB: per-128-node-bucket sort -> srcS/kS + off (391 blocks, full chip)
//   conv1+mlp1: half-wave/node, 16-lane group per edge, dual k-acc
//   conv2:      wave per node, 8-lane group per edge, float4 row gather
//   mlp2:       64 nodes/256thr; W2a/W2b bf16-packed IN LDS (no L2 W stream);
//               X from global (L1-resident), H bf16-packed in LDS
//
// NOTE (round-7): NEVER atomicAdd on __shared__ float in hot loops (678us).
// NOTE (mlp2 series R8-R13): 64-node/256thr acc[4][8] is the right shape
//   (16 FMA/load); grid is capped at 782 blocks -> 3 waves/SIMD, so W
//   streaming from L2 (~200cyc) cannot be hidden by TLP (41% VALUBusy).
//   Fix here: W LDS-resident (one 64KB stage per block), inner loop is
//   LDS+L1 only. 16-node blocks (R12) and LDS-free hT (R11) both worse.

#define EPSV 1e-12f
#define CHUNK 2048      // edges per partA block
#define NB2 512         // bucket slot array size (nbuck = ceil(N/128) = 391)
#define BSH 7           // bucket shift: 128 nodes per bucket
#define BNODES 128      // nodes per bucket
#define BCPAD 16        // bcur padding stride (ints)
#define WA_STRIDE 132   // wpkA row stride (uints): rotates banks by 4 per k2
#define WB_STRIDE 68    // wpkB row stride

typedef unsigned short ushort_t;
typedef unsigned int uint_t;

// ---- detect whether edge_index buffer is int64 (odd int32 words all zero) ----
__global__ void detect_i64_kernel(const int* ei, int* flag) {
    int lane = threadIdx.x;
    int nonzero = 0;
    for (int i = lane; i < 1024; i += 64) {
        if (ei[2 * i + 1] != 0) nonzero = 1;
    }
    unsigned long long b = __ballot(nonzero);
    if (lane == 0) *flag = (b == 0ull) ? 1 : 0;   // 1 => int64 layout
}

__device__ __forceinline__ void load_edge(const int* ei, int e, int E, int flag,
                                          int& src, int& dst) {
    if (flag) {            // int64 storage: low words at even int32 indices
        src = ei[2 * e];
        dst = ei[2 * E + 2 * e];
    } else {               // int32 storage
        src = ei[e];
        dst = ei[E + e];
    }
}

// ---- bucket histogram: LDS-privatized, vectorized dst loads ----
__global__ __launch_bounds__(256) void bhist_kernel(
        const int* __restrict__ ei, const int* __restrict__ flagp,
        int* __restrict__ cntmat, int E) {
    __shared__ int l[NB2];
    for (int i = threadIdx.x; i < NB2; i += 256) l[i] = 0;
    __syncthreads();
    int flag = *flagp;
    int stride = gridDim.x * 256;
    int gid = blockIdx.x * 256 + threadIdx.x;
    if ((E & 3) == 0) {
        if (flag) {
            const int4* p = (const int4*)(ei + 2 * (size_t)E);  // dst pairs
            int total = E >> 1;
            for (int i = gid; i < total; i += stride) {
                int4 v = p[i];
                atomicAdd(&l[v.x >> BSH], 1);
                atomicAdd(&l[v.z >> BSH], 1);
            }
        } else {
            const int4* p = (const int4*)(ei + (size_t)E);
            int total = E >> 2;
            for (int i = gid; i < total; i += stride) {
                int4 v = p[i];
                atomicAdd(&l[v.x >> BSH], 1);
                atomicAdd(&l[v.y >> BSH], 1);
                atomicAdd(&l[v.z >> BSH], 1);
                atomicAdd(&l[v.w >> BSH], 1);
            }
        }
    } else {
        for (int e = gid; e < E; e += stride) {
            int dst = flag ? ei[2 * (size_t)E + 2 * e] : ei[(size_t)E + e];
            atomicAdd(&l[dst >> BSH], 1);
        }
    }
    __syncthreads();
    for (int i = threadIdx.x; i < NB2; i += 256)
        cntmat[blockIdx.x * NB2 + i] = l[i];
}

// ---- column-sum cntmat + exclusive scan of bucket counts (512 threads) ----
__global__ __launch_bounds__(NB2) void bscan_kernel(
        const int* __restrict__ cntmat,
        int* __restrict__ bbase, int* __restrict__ bcur,
        int* __restrict__ off,
        int nbuck, int E, int nrows, int N) {
    __shared__ int s[NB2];
    int t = threadIdx.x;            // blockDim = NB2
    int c = 0;
    for (int i = 0; i < nrows; ++i) c += cntmat[i * NB2 + t];
    s[t] = c;
    __syncthreads();
    for (int d = 1; d < NB2; d <<= 1) {
        int v = (t >= d) ? s[t - d] : 0;
        __syncthreads();
        s[t] += v;
        __syncthreads();
    }
    int excl = s[t] - c;
    if (t < nbuck) { bbase[t] = excl; bcur[t * BCPAD] = excl; }
    if (t == 0) { bbase[nbuck] = E; off[N] = E; }
}

// ---- partA: bucket-partition edges by dst>>7, LDS-staged ----
__global__ __launch_bounds__(256) void partA_kernel(
        const float* __restrict__ K, const int* __restrict__ ei,
        const int* __restrict__ flagp, int* __restrict__ bcur,
        int4* __restrict__ staging, int E) {
    __shared__ int cnt[NB2];
    __shared__ int bexc[NB2];
    __shared__ int gbase[NB2];
    __shared__ int scanbuf[256];
    __shared__ int4 stage[CHUNK];     // 32 KB

    int flag = *flagp;
    int e0 = blockIdx.x * CHUNK;
    int tot = min(CHUNK, E - e0);
    int t = threadIdx.x;

    for (int b = t; b < NB2; b += 256) cnt[b] = 0;
    __syncthreads();

    int  myslot[CHUNK / 256];
    int  mybk[CHUNK / 256];
    int4 myrec[CHUNK / 256];
#pragma unroll
    for (int it = 0; it < CHUNK / 256; ++it) {
        int e = e0 + it * 256 + t;
        mybk[it] = -1;
        if (e < E) {
            int src, dst;
            load_edge(ei, e, E, flag, src, dst);
            int bk = dst >> BSH;
            mybk[it] = bk;
            myrec[it] = make_int4(src, __float_as_int(K[e]),
                                  __float_as_int(K[E + e]), dst);
            myslot[it] = atomicAdd(&cnt[bk], 1);
        }
    }
    __syncthreads();

    // scan 512 buckets: thread t owns buckets 2t, 2t+1
    int c0 = cnt[2 * t];
    int c1 = cnt[2 * t + 1];
    int cs = c0 + c1;
    scanbuf[t] = cs;
    __syncthreads();
    for (int d = 1; d < 256; d <<= 1) {
        int v = (t >= d) ? scanbuf[t - d] : 0;
        __syncthreads();
        scanbuf[t] += v;
        __syncthreads();
    }
    int excl = scanbuf[t] - cs;
    bexc[2 * t] = excl;
    bexc[2 * t + 1] = excl + c0;
    gbase[2 * t]     = c0 ? atomicAdd(&bcur[(2 * t) * BCPAD], c0) : 0;
    gbase[2 * t + 1] = c1 ? atomicAdd(&bcur[(2 * t + 1) * BCPAD], c1) : 0;
    __syncthreads();

#pragma unroll
    for (int it = 0; it < CHUNK / 256; ++it) {
        if (mybk[it] >= 0) stage[bexc[mybk[it]] + myslot[it]] = myrec[it];
    }
    __syncthreads();

    for (int i = t; i < tot; i += 256) {
        int4 r = stage[i];
        int bk = r.w >> BSH;
        staging[gbase[bk] + (i - bexc[bk])] = r;
    }
}

// ---- partB: one block per 128-node bucket; LDS hist+scan -> off; place ----
__global__ __launch_bounds__(256) void partB_kernel(
        const int4* __restrict__ staging, const int* __restrict__ bbase,
        int* __restrict__ off, int* __restrict__ srcS,
        float2* __restrict__ kS, int N) {
    __shared__ int lcnt[BNODES];
    __shared__ int lscan[BNODES];

    int b = blockIdx.x;
    int nodeBase = b << BSH;
    int s0 = bbase[b];
    int s1 = bbase[b + 1];
    int t = threadIdx.x;

    if (t < BNODES) lcnt[t] = 0;
    __syncthreads();

    for (int i = s0 + t; i < s1; i += 256)
        atomicAdd(&lcnt[staging[i].w - nodeBase], 1);
    __syncthreads();

    if (t < BNODES) lscan[t] = lcnt[t];
    __syncthreads();
    for (int d = 1; d < BNODES; d <<= 1) {
        int v = 0;
        if (t < BNODES && t >= d) v = lscan[t - d];
        __syncthreads();
        if (t < BNODES) lscan[t] += v;
        __syncthreads();
    }
    if (t < BNODES) {
        int node = nodeBase + t;
        if (node < N) {
            int c = lcnt[t];
            int o = s0 + lscan[t] - c;   // exclusive offset, absolute
            off[node] = o;
            lcnt[t] = o;                 // becomes the cursor
        }
    }
    __syncthreads();

    for (int i = s0 + t; i < s1; i += 256) {
        int4 r = staging[i];
        int pos = atomicAdd(&lcnt[r.w - nodeBase], 1);
        srcS[pos] = r.x;
        kS[pos] = make_float2(__int_as_float(r.y), __int_as_float(r.z));
    }
}

// ---- conv1 + MLP1: half-wave per node; 16-lane group per edge ----
__global__ __launch_bounds__(256) void conv1_mlp1_kernel(
        const float* __restrict__ x, const int* __restrict__ srcS,
        const float2* __restrict__ kS, const int* __restrict__ off,
        const float* __restrict__ W1, const float* __restrict__ b1,
        float* __restrict__ h1, int N) {
    __shared__ float w[1024];
    __shared__ float bsh[32];
    for (int i = threadIdx.x; i < 1024; i += 256) w[i] = W1[i];
    if (threadIdx.x < 32) bsh[threadIdx.x] = b1[threadIdx.x];
    __syncthreads();

    int hw = threadIdx.x >> 5;        // half-wave 0..7 -> node
    int lane = threadIdx.x & 31;
    int node = blockIdx.x * 8 + hw;
    if (node >= N) return;

    int ch = lane & 15;
    int grp = lane >> 4;              // 0/1: edge parity
    int start = off[node];
    int deg = off[node + 1] - start;

    float a0 = 0.f, a1 = 0.f;
    int j = grp;
    for (; j + 6 < deg; j += 8) {     // edges j, j+2, j+4, j+6
        int p = start + j;
        int s0 = srcS[p], s1 = srcS[p + 2], s2 = srcS[p + 4], s3 = srcS[p + 6];
        float2 k0 = kS[p], k1 = kS[p + 2], k2 = kS[p + 4], k3 = kS[p + 6];
        float v0 = x[s0 * 16 + ch];
        float v1 = x[s1 * 16 + ch];
        float v2 = x[s2 * 16 + ch];
        float v3 = x[s3 * 16 + ch];
        a0 += k0.x * v0; a1 += k0.y * v0;
        a0 += k1.x * v1; a1 += k1.y * v1;
        a0 += k2.x * v2; a1 += k2.y * v2;
        a0 += k3.x * v3; a1 += k3.y * v3;
    }
    for (; j < deg; j += 2) {
        int p = start + j;
        int s = srcS[p];
        float2 kk = kS[p];
        float v = x[s * 16 + ch];
        a0 += kk.x * v; a1 += kk.y * v;
    }
    a0 += __shfl_xor(a0, 16, 32);
    a1 += __shfl_xor(a1, 16, 32);
    float acc = grp ? a1 : a0;

    float o = bsh[lane];
#pragma unroll
    for (int q = 0; q < 32; q++) o += __shfl(acc, q, 32) * w[q * 32 + lane];
    o = fmaxf(o, 0.f);
    float ss = o * o;
#pragma unroll
    for (int m = 16; m >= 1; m >>= 1) ss += __shfl_xor(ss, m, 32);
    h1[node * 32 + lane] = o / fmaxf(sqrtf(ss), EPSV);
}

// ---- conv2: wave per node; 8-lane group per edge; float4 row gather ----
__global__ __launch_bounds__(256) void conv2_gather_kernel(
        const float* __restrict__ h1, const int* __restrict__ srcS,
        const float2* __restrict__ kS, const int* __restrict__ off,
        float* __restrict__ h2, int N) {
    int wid = threadIdx.x >> 6;
    int lane = threadIdx.x & 63;
    int node = blockIdx.x * 4 + wid;
    if (node >= N) return;

    int grp = lane >> 3;              // 0..7: edge index mod 8
    int cq = lane & 7;                // channel quad: ch = cq*4..cq*4+3
    int start = off[node];
    int deg = off[node + 1] - start;

    float a00 = 0.f, a01 = 0.f, a02 = 0.f, a03 = 0.f;   // k0 * row[cq*4..]
    float a10 = 0.f, a11 = 0.f, a12 = 0.f, a13 = 0.f;   // k1 * row[cq*4..]
    int j = grp;
    for (; j + 8 < deg; j += 16) {    // edges j, j+8
        int p0 = start + j, p1 = start + j + 8;
        int s0 = srcS[p0], s1 = srcS[p1];
        float2 k0 = kS[p0], k1 = kS[p1];
        float4 v0 = *(const float4*)&h1[s0 * 32 + cq * 4];
        float4 v1 = *(const float4*)&h1[s1 * 32 + cq * 4];
        a00 += k0.x * v0.x; a01 += k0.x * v0.y; a02 += k0.x * v0.z; a03 += k0.x * v0.w;
        a10 += k0.y * v0.x; a11 += k0.y * v0.y; a12 += k0.y * v0.z; a13 += k0.y * v0.w;
        a00 += k1.x * v1.x; a01 += k1.x * v1.y; a02 += k1.x * v1.z; a03 += k1.x * v1.w;
        a10 += k1.y * v1.x; a11 += k1.y * v1.y; a12 += k1.y * v1.z; a13 += k1.y * v1.w;
    }
    for (; j < deg; j += 8) {
        int p = start + j;
        int s = srcS[p];
        float2 kk = kS[p];
        float4 v = *(const float4*)&h1[s * 32 + cq * 4];
        a00 += kk.x * v.x; a01 += kk.x * v.y; a02 += kk.x * v.z; a03 += kk.x * v.w;
        a10 += kk.y * v.x; a11 += kk.y * v.y; a12 += kk.y * v.z; a13 += kk.y * v.w;
    }

#pragma unroll
    for (int m = 8; m < 64; m <<= 1) {
        a00 += __shfl_xor(a00, m, 64); a01 += __shfl_xor(a01, m, 64);
        a02 += __shfl_xor(a02, m, 64); a03 += __shfl_xor(a03, m, 64);
        a10 += __shfl_xor(a10, m, 64); a11 += __shfl_xor(a11, m, 64);
        a12 += __shfl_xor(a12, m, 64); a13 += __shfl_xor(a13, m, 64);
    }
    if (grp == 0) {
        float4 o = make_float4(a00, a01, a02, a03);
        *(float4*)&h2[(size_t)node * 64 + cq * 4] = o;
    } else if (grp == 1) {
        float4 o = make_float4(a10, a11, a12, a13);
        *(float4*)&h2[(size_t)node * 64 + 32 + cq * 4] = o;
    }
}

// ---- bf16 pack/unpack helpers ----
__device__ __forceinline__ ushort_t f2bf(float f) {
    uint_t u = __float_as_uint(f);
    uint_t r = u + 0x7FFFu + ((u >> 16) & 1u);
    return (ushort_t)(r >> 16);
}
__device__ __forceinline__ uint_t pack2(float a, float b) {
    return (uint_t)f2bf(a) | ((uint_t)f2bf(b) << 16);
}
__device__ __forceinline__ float unpk_lo(uint_t u) {
    return __uint_as_float(u << 16);
}
__device__ __forceinline__ float unpk_hi(uint_t u) {
    return __uint_as_float(u & 0xFFFF0000u);
}

// ---- MLP2: 64 nodes/256thr; W2a/W2b bf16-packed in LDS; X from global ----
// wpkA[k2][c] = bf16(W2a[2k2][c]) | bf16(W2a[2k2+1][c])<<16  (k2<32, c<128)
// wpkB[k2][c] = same for W2b (k2<64, c<64)
// hs2[c2][n]  = bf16-packed H^T pairs along c (as R13)
// Thread (rg=tid>>4, cg=tid&15): nodes rg*4..+3, GEMM1 cols cg*8..+7,
// GEMM2 cols cg*4..+3. Inner loops touch only LDS + L1-resident X.
__global__ __launch_bounds__(256) void mlp2_kernel(
        const float* __restrict__ h2,
        const float* __restrict__ W2a,
        const float* __restrict__ b2a,
        const float* __restrict__ W2b,
        const float* __restrict__ b2b,
        float* __restrict__ out, int N) {
    __shared__ uint_t wpkA[32 * WA_STRIDE];   // 16.9 KB
    __shared__ uint_t wpkB[64 * WB_STRIDE];   // 17.4 KB
    __shared__ uint_t hs2[64 * 68];           // 17.4 KB

    int tid = threadIdx.x;
    int n0 = blockIdx.x * 64;

    // stage W2a as k-pair-packed bf16 (coalesced: consecutive tid -> cols)
    for (int i = tid; i < 32 * 128; i += 256) {
        int k2 = i >> 7, c = i & 127;
        wpkA[k2 * WA_STRIDE + c] = pack2(W2a[(size_t)(2 * k2) * 128 + c],
                                         W2a[(size_t)(2 * k2 + 1) * 128 + c]);
    }
    // stage W2b
    for (int i = tid; i < 64 * 64; i += 256) {
        int k2 = i >> 6, c = i & 63;
        wpkB[k2 * WB_STRIDE + c] = pack2(W2b[(size_t)(2 * k2) * 64 + c],
                                         W2b[(size_t)(2 * k2 + 1) * 64 + c]);
    }
    __syncthreads();

    int rg = tid >> 4;     // 0..15: nodes rg*4..+3
    int cg = tid & 15;
    int nb = rg * 4;

    // GEMM1: H[nb..nb+3][cg*8..+7], X from global (block X is L1-resident)
    float acc[4][8];
#pragma unroll
    for (int j = 0; j < 4; j++)
#pragma unroll
        for (int i = 0; i < 8; i++) acc[j][i] = 0.0f;

    for (int k4 = 0; k4 < 16; ++k4) {
        float4 xr[4];
#pragma unroll
        for (int j = 0; j < 4; j++) {
            int n = n0 + nb + j;
            xr[j] = (n < N) ? *(const float4*)&h2[(size_t)n * 64 + k4 * 4]
                            : make_float4(0.f, 0.f, 0.f, 0.f);
        }
        // s = 0: k = 4k4, 4k4+1 (pair k2 = 2k4)
        {
            int k2 = k4 * 2;
            uint4 wa0 = *(const uint4*)&wpkA[k2 * WA_STRIDE + cg * 8];
            uint4 wa1 = *(const uint4*)&wpkA[k2 * WA_STRIDE + cg * 8 + 4];
            float wlo[8] = {unpk_lo(wa0.x), unpk_lo(wa0.y), unpk_lo(wa0.z),
                            unpk_lo(wa0.w), unpk_lo(wa1.x), unpk_lo(wa1.y),
                            unpk_lo(wa1.z), unpk_lo(wa1.w)};
            float whi[8] = {unpk_hi(wa0.x), unpk_hi(wa0.y), unpk_hi(wa0.z),
                            unpk_hi(wa0.w), unpk_hi(wa1.x), unpk_hi(wa1.y),
                            unpk_hi(wa1.z), unpk_hi(wa1.w)};
#pragma unroll
            for (int j = 0; j < 4; j++) {
                float x0 = xr[j].x, x1 = xr[j].y;
#pragma unroll
                for (int i = 0; i < 8; i++)
                    acc[j][i] += x0 * wlo[i] + x1 * whi[i];
            }
        }
        // s = 1: k = 4k4+2, 4k4+3 (pair k2 = 2k4+1)
        {
            int k2 = k4 * 2 + 1;
            uint4 wa0 = *(const uint4*)&wpkA[k2 * WA_STRIDE + cg * 8];
            uint4 wa1 = *(const uint4*)&wpkA[k2 * WA_STRIDE + cg * 8 + 4];
            float wlo[8] = {unpk_lo(wa0.x), unpk_lo(wa0.y), unpk_lo(wa0.z),
                            unpk_lo(wa0.w), unpk_lo(wa1.x), unpk_lo(wa1.y),
                            unpk_lo(wa1.z), unpk_lo(wa1.w)};
            float whi[8] = {unpk_hi(wa0.x), unpk_hi(wa0.y), unpk_hi(wa0.z),
                            unpk_hi(wa0.w), unpk_hi(wa1.x), unpk_hi(wa1.y),
                            unpk_hi(wa1.z), unpk_hi(wa1.w)};
#pragma unroll
            for (int j = 0; j < 4; j++) {
                float x0 = xr[j].z, x1 = xr[j].w;
#pragma unroll
                for (int i = 0; i < 8; i++)
                    acc[j][i] += x0 * wlo[i] + x1 * whi[i];
            }
        }
    }

    // bias + relu + bf16-pack store of H^T (pairs along c)
#pragma unroll
    for (int i = 0; i < 4; i++) {
        int c = cg * 8 + 2 * i;
        float b0 = b2a[c], b1 = b2a[c + 1];
        uint4 hp;
        hp.x = pack2(fmaxf(acc[0][2 * i] + b0, 0.f), fmaxf(acc[0][2 * i + 1] + b1, 0.f));
        hp.y = pack2(fmaxf(acc[1][2 * i] + b0, 0.f), fmaxf(acc[1][2 * i + 1] + b1, 0.f));
        hp.z = pack2(fmaxf(acc[2][2 * i] + b0, 0.f), fmaxf(acc[2][2 * i + 1] + b1, 0.f));
        hp.w = pack2(fmaxf(acc[3][2 * i] + b0, 0.f), fmaxf(acc[3][2 * i + 1] + b1, 0.f));
        *(uint4*)&hs2[(cg * 4 + i) * 68 + nb] = hp;
    }
    __syncthreads();

    // GEMM2: O[nb..nb+3][cg*4..+3], H and W2b both from LDS
    float a2[4][4];
#pragma unroll
    for (int j = 0; j < 4; j++)
#pragma unroll
        for (int i = 0; i < 4; i++) a2[j][i] = 0.0f;

    for (int k2 = 0; k2 < 64; ++k2) {
        uint4 hp = *(const uint4*)&hs2[k2 * 68 + nb];
        uint4 wb = *(const uint4*)&wpkB[k2 * WB_STRIDE + cg * 4];
        float hlo[4] = {unpk_lo(hp.x), unpk_lo(hp.y), unpk_lo(hp.z), unpk_lo(hp.w)};
        float hhi[4] = {unpk_hi(hp.x), unpk_hi(hp.y), unpk_hi(hp.z), unpk_hi(hp.w)};
        float wblo[4] = {unpk_lo(wb.x), unpk_lo(wb.y), unpk_lo(wb.z), unpk_lo(wb.w)};
        float wbhi[4] = {unpk_hi(wb.x), unpk_hi(wb.y), unpk_hi(wb.z), unpk_hi(wb.w)};
#pragma unroll
        for (int j = 0; j < 4; j++) {
#pragma unroll
            for (int i = 0; i < 4; i++)
                a2[j][i] += hlo[j] * wblo[i] + hhi[j] * wbhi[i];
        }
    }

#pragma unroll
    for (int i = 0; i < 4; i++) {
        float bi = b2b[cg * 4 + i];
#pragma unroll
        for (int j = 0; j < 4; j++) a2[j][i] += bi;
    }

    // l2norm per node row: reduce squares across the 16 cg lanes
#pragma unroll
    for (int j = 0; j < 4; j++) {
        float ss = a2[j][0] * a2[j][0] + a2[j][1] * a2[j][1] +
                   a2[j][2] * a2[j][2] + a2[j][3] * a2[j][3];
#pragma unroll
        for (int m = 1; m < 16; m <<= 1) ss += __shfl_xor(ss, m, 64);
        float invn = 1.0f / fmaxf(sqrtf(ss), EPSV);
        int n = n0 + nb + j;
        if (n < N) {
            float4 o = make_float4(a2[j][0] * invn, a2[j][1] * invn,
                                   a2[j][2] * invn, a2[j][3] * invn);
            *(float4*)&out[(size_t)n * 64 + cg * 4] = o;
        }
    }
}

extern "C" void kernel_launch(void* const* d_in, const int* in_sizes, int n_in,
                              void* d_out, int out_size, void* d_ws, size_t ws_size,
                              hipStream_t stream) {
    const float* x   = (const float*)d_in[0];
    const float* K   = (const float*)d_in[1];
    const int*   ei  = (const int*)d_in[2];
    const float* W1  = (const float*)d_in[3];
    const float* b1  = (const float*)d_in[4];
    const float* W2a = (const float*)d_in[5];
    const float* b2a = (const float*)d_in[6];
    const float* W2b = (const float*)d_in[7];
    const float* b2b = (const float*)d_in[8];
    float* out = (float*)d_out;

    const int D  = 16;
    const int NK = 2;
    const int N  = in_sizes[0] / D;        // 50000
    const int E  = in_sizes[1] / NK;       // 1600000
    const int nbuck = (N + BNODES - 1) >> BSH;  // 391 <= NB2
    const int HROWS = 256;                 // bhist blocks

    // workspace layout:
    //   region0 (overlaid in time):
    //     phase 1 (CSR build): staging int4[E]      (E*16 bytes)
    //     phase 2+3:           h2[N*64] | h1[N*32]  (N*384 bytes)
    //   then: srcS[E] | kS[E] (float2) | off[N+1] | cntmat[HROWS*NB2] |
    //         bbase[NB2+1] | bcur[NB2*BCPAD] | flag[1]
    size_t region0 = (size_t)E * 16;
    size_t hbytes  = (size_t)N * 96 * 4;
    if (hbytes > region0) region0 = hbytes;

    float* h2       = (float*)d_ws;
    float* h1       = h2 + (size_t)N * 64;
    int4* staging   = (int4*)d_ws;
    int* srcS       = (int*)((char*)d_ws + region0);
    float2* kS      = (float2*)(srcS + (size_t)E);
    int* off        = (int*)(kS + (size_t)E);
    int* cntmat     = off + (N + 1);
    int* bbase      = cntmat + HROWS * NB2;
    int* bcur       = bbase + NB2 + 1;
    int* flag       = bcur + NB2 * BCPAD;

    detect_i64_kernel<<<1, 64, 0, stream>>>(ei, flag);
    bhist_kernel<<<HROWS, 256, 0, stream>>>(ei, flag, cntmat, E);
    bscan_kernel<<<1, NB2, 0, stream>>>(cntmat, bbase, bcur, off,
                                        nbuck, E, HROWS, N);

    int ablocks = (E + CHUNK - 1) / CHUNK;
    partA_kernel<<<ablocks, 256, 0, stream>>>(K, ei, flag, bcur, staging, E);
    partB_kernel<<<nbuck, 256, 0, stream>>>(staging, bbase, off, srcS, kS, N);

    conv1_mlp1_kernel<<<(N + 7) / 8, 256, 0, stream>>>(x, srcS, kS, off,
                                                       W1, b1, h1, N);
    conv2_gather_kernel<<<(N + 3) / 4, 256, 0, stream>>>(h1, srcS, kS, off,
                                                         h2, N);
    mlp2_kernel<<<(N + 63) / 64, 256, 0, stream>>>(h2, W2a, b2a, W2b, b2b,
                                                   out, N);
}

// Round 15
// 181.343 us; speedup vs baseline: 1.2060x; 1.2060x over previous
//
#include <hip/hip_runtime.h>
#include <hip/hip_bf16.h>

// Pipeline (N=50000, E=1.6M, D=16, NK=2):
//   bhist/bscan/partA/partB: dst-sorted CSR build (unchanged from R13/14)
//   conv1+mlp1: half-wave/node, 16-lane group per edge, dual k-acc
//   conv2:      wave per node, 8-lane group per edge, float4 row gather
//   packW:      pack W2a/W2b into MFMA B-fragment order (bf16), 1 tiny launch
//   mlp2:       MFMA! 64 nodes/block, 4 waves x 16 nodes; 32x mfma_16x16x32_bf16
//               per wave; H through 17KB LDS strip; l2norm via shfl_xor(16)
//
// NOTE (round-7): NEVER atomicAdd on __shared__ float in hot loops (678us).
// NOTE (mlp2 series R8-R14): vector-ALU mlp2 plateaued at 45-56us across 7
//   designs (latency-bound at 3 waves/SIMD; W-stream/conflicts/unpack always
//   fill the slack). Fix = matrix cores (Guideline 10): MFMA is per-wave,
//   C/D layout col=lane&15,row=(lane>>4)*4+reg (m89-verified), A row=lane&15
//   k=(lane>>4)*8+i. B-frags pre-packed to fragment order -> coalesced uint4.

#define EPSV 1e-12f
#define CHUNK 2048      // edges per partA block
#define NB2 512         // bucket slot array size (nbuck = ceil(N/128) = 391)
#define BSH 7           // bucket shift: 128 nodes per bucket
#define BNODES 128      // nodes per bucket
#define BCPAD 16        // bcur padding stride (ints)

typedef unsigned short ushort_t;
typedef unsigned int uint_t;
typedef __attribute__((ext_vector_type(8))) short bf16x8;
typedef __attribute__((ext_vector_type(4))) float f32x4;

// ---- detect whether edge_index buffer is int64 (odd int32 words all zero) ----
__global__ void detect_i64_kernel(const int* ei, int* flag) {
    int lane = threadIdx.x;
    int nonzero = 0;
    for (int i = lane; i < 1024; i += 64) {
        if (ei[2 * i + 1] != 0) nonzero = 1;
    }
    unsigned long long b = __ballot(nonzero);
    if (lane == 0) *flag = (b == 0ull) ? 1 : 0;   // 1 => int64 layout
}

__device__ __forceinline__ void load_edge(const int* ei, int e, int E, int flag,
                                          int& src, int& dst) {
    if (flag) {            // int64 storage: low words at even int32 indices
        src = ei[2 * e];
        dst = ei[2 * E + 2 * e];
    } else {               // int32 storage
        src = ei[e];
        dst = ei[E + e];
    }
}

// ---- bucket histogram: LDS-privatized, vectorized dst loads ----
__global__ __launch_bounds__(256) void bhist_kernel(
        const int* __restrict__ ei, const int* __restrict__ flagp,
        int* __restrict__ cntmat, int E) {
    __shared__ int l[NB2];
    for (int i = threadIdx.x; i < NB2; i += 256) l[i] = 0;
    __syncthreads();
    int flag = *flagp;
    int stride = gridDim.x * 256;
    int gid = blockIdx.x * 256 + threadIdx.x;
    if ((E & 3) == 0) {
        if (flag) {
            const int4* p = (const int4*)(ei + 2 * (size_t)E);  // dst pairs
            int total = E >> 1;
            for (int i = gid; i < total; i += stride) {
                int4 v = p[i];
                atomicAdd(&l[v.x >> BSH], 1);
                atomicAdd(&l[v.z >> BSH], 1);
            }
        } else {
            const int4* p = (const int4*)(ei + (size_t)E);
            int total = E >> 2;
            for (int i = gid; i < total; i += stride) {
                int4 v = p[i];
                atomicAdd(&l[v.x >> BSH], 1);
                atomicAdd(&l[v.y >> BSH], 1);
                atomicAdd(&l[v.z >> BSH], 1);
                atomicAdd(&l[v.w >> BSH], 1);
            }
        }
    } else {
        for (int e = gid; e < E; e += stride) {
            int dst = flag ? ei[2 * (size_t)E + 2 * e] : ei[(size_t)E + e];
            atomicAdd(&l[dst >> BSH], 1);
        }
    }
    __syncthreads();
    for (int i = threadIdx.x; i < NB2; i += 256)
        cntmat[blockIdx.x * NB2 + i] = l[i];
}

// ---- column-sum cntmat + exclusive scan of bucket counts (512 threads) ----
__global__ __launch_bounds__(NB2) void bscan_kernel(
        const int* __restrict__ cntmat,
        int* __restrict__ bbase, int* __restrict__ bcur,
        int* __restrict__ off,
        int nbuck, int E, int nrows, int N) {
    __shared__ int s[NB2];
    int t = threadIdx.x;            // blockDim = NB2
    int c = 0;
    for (int i = 0; i < nrows; ++i) c += cntmat[i * NB2 + t];
    s[t] = c;
    __syncthreads();
    for (int d = 1; d < NB2; d <<= 1) {
        int v = (t >= d) ? s[t - d] : 0;
        __syncthreads();
        s[t] += v;
        __syncthreads();
    }
    int excl = s[t] - c;
    if (t < nbuck) { bbase[t] = excl; bcur[t * BCPAD] = excl; }
    if (t == 0) { bbase[nbuck] = E; off[N] = E; }
}

// ---- partA: bucket-partition edges by dst>>7, LDS-staged ----
__global__ __launch_bounds__(256) void partA_kernel(
        const float* __restrict__ K, const int* __restrict__ ei,
        const int* __restrict__ flagp, int* __restrict__ bcur,
        int4* __restrict__ staging, int E) {
    __shared__ int cnt[NB2];
    __shared__ int bexc[NB2];
    __shared__ int gbase[NB2];
    __shared__ int scanbuf[256];
    __shared__ int4 stage[CHUNK];     // 32 KB

    int flag = *flagp;
    int e0 = blockIdx.x * CHUNK;
    int tot = min(CHUNK, E - e0);
    int t = threadIdx.x;

    for (int b = t; b < NB2; b += 256) cnt[b] = 0;
    __syncthreads();

    int  myslot[CHUNK / 256];
    int  mybk[CHUNK / 256];
    int4 myrec[CHUNK / 256];
#pragma unroll
    for (int it = 0; it < CHUNK / 256; ++it) {
        int e = e0 + it * 256 + t;
        mybk[it] = -1;
        if (e < E) {
            int src, dst;
            load_edge(ei, e, E, flag, src, dst);
            int bk = dst >> BSH;
            mybk[it] = bk;
            myrec[it] = make_int4(src, __float_as_int(K[e]),
                                  __float_as_int(K[E + e]), dst);
            myslot[it] = atomicAdd(&cnt[bk], 1);
        }
    }
    __syncthreads();

    // scan 512 buckets: thread t owns buckets 2t, 2t+1
    int c0 = cnt[2 * t];
    int c1 = cnt[2 * t + 1];
    int cs = c0 + c1;
    scanbuf[t] = cs;
    __syncthreads();
    for (int d = 1; d < 256; d <<= 1) {
        int v = (t >= d) ? scanbuf[t - d] : 0;
        __syncthreads();
        scanbuf[t] += v;
        __syncthreads();
    }
    int excl = scanbuf[t] - cs;
    bexc[2 * t] = excl;
    bexc[2 * t + 1] = excl + c0;
    gbase[2 * t]     = c0 ? atomicAdd(&bcur[(2 * t) * BCPAD], c0) : 0;
    gbase[2 * t + 1] = c1 ? atomicAdd(&bcur[(2 * t + 1) * BCPAD], c1) : 0;
    __syncthreads();

#pragma unroll
    for (int it = 0; it < CHUNK / 256; ++it) {
        if (mybk[it] >= 0) stage[bexc[mybk[it]] + myslot[it]] = myrec[it];
    }
    __syncthreads();

    for (int i = t; i < tot; i += 256) {
        int4 r = stage[i];
        int bk = r.w >> BSH;
        staging[gbase[bk] + (i - bexc[bk])] = r;
    }
}

// ---- partB: one block per 128-node bucket; LDS hist+scan -> off; place ----
__global__ __launch_bounds__(256) void partB_kernel(
        const int4* __restrict__ staging, const int* __restrict__ bbase,
        int* __restrict__ off, int* __restrict__ srcS,
        float2* __restrict__ kS, int N) {
    __shared__ int lcnt[BNODES];
    __shared__ int lscan[BNODES];

    int b = blockIdx.x;
    int nodeBase = b << BSH;
    int s0 = bbase[b];
    int s1 = bbase[b + 1];
    int t = threadIdx.x;

    if (t < BNODES) lcnt[t] = 0;
    __syncthreads();

    for (int i = s0 + t; i < s1; i += 256)
        atomicAdd(&lcnt[staging[i].w - nodeBase], 1);
    __syncthreads();

    if (t < BNODES) lscan[t] = lcnt[t];
    __syncthreads();
    for (int d = 1; d < BNODES; d <<= 1) {
        int v = 0;
        if (t < BNODES && t >= d) v = lscan[t - d];
        __syncthreads();
        if (t < BNODES) lscan[t] += v;
        __syncthreads();
    }
    if (t < BNODES) {
        int node = nodeBase + t;
        if (node < N) {
            int c = lcnt[t];
            int o = s0 + lscan[t] - c;   // exclusive offset, absolute
            off[node] = o;
            lcnt[t] = o;                 // becomes the cursor
        }
    }
    __syncthreads();

    for (int i = s0 + t; i < s1; i += 256) {
        int4 r = staging[i];
        int pos = atomicAdd(&lcnt[r.w - nodeBase], 1);
        srcS[pos] = r.x;
        kS[pos] = make_float2(__int_as_float(r.y), __int_as_float(r.z));
    }
}

// ---- conv1 + MLP1: half-wave per node; 16-lane group per edge ----
__global__ __launch_bounds__(256) void conv1_mlp1_kernel(
        const float* __restrict__ x, const int* __restrict__ srcS,
        const float2* __restrict__ kS, const int* __restrict__ off,
        const float* __restrict__ W1, const float* __restrict__ b1,
        float* __restrict__ h1, int N) {
    __shared__ float w[1024];
    __shared__ float bsh[32];
    for (int i = threadIdx.x; i < 1024; i += 256) w[i] = W1[i];
    if (threadIdx.x < 32) bsh[threadIdx.x] = b1[threadIdx.x];
    __syncthreads();

    int hw = threadIdx.x >> 5;        // half-wave 0..7 -> node
    int lane = threadIdx.x & 31;
    int node = blockIdx.x * 8 + hw;
    if (node >= N) return;

    int ch = lane & 15;
    int grp = lane >> 4;              // 0/1: edge parity
    int start = off[node];
    int deg = off[node + 1] - start;

    float a0 = 0.f, a1 = 0.f;
    int j = grp;
    for (; j + 6 < deg; j += 8) {     // edges j, j+2, j+4, j+6
        int p = start + j;
        int s0 = srcS[p], s1 = srcS[p + 2], s2 = srcS[p + 4], s3 = srcS[p + 6];
        float2 k0 = kS[p], k1 = kS[p + 2], k2 = kS[p + 4], k3 = kS[p + 6];
        float v0 = x[s0 * 16 + ch];
        float v1 = x[s1 * 16 + ch];
        float v2 = x[s2 * 16 + ch];
        float v3 = x[s3 * 16 + ch];
        a0 += k0.x * v0; a1 += k0.y * v0;
        a0 += k1.x * v1; a1 += k1.y * v1;
        a0 += k2.x * v2; a1 += k2.y * v2;
        a0 += k3.x * v3; a1 += k3.y * v3;
    }
    for (; j < deg; j += 2) {
        int p = start + j;
        int s = srcS[p];
        float2 kk = kS[p];
        float v = x[s * 16 + ch];
        a0 += kk.x * v; a1 += kk.y * v;
    }
    a0 += __shfl_xor(a0, 16, 32);
    a1 += __shfl_xor(a1, 16, 32);
    float acc = grp ? a1 : a0;

    float o = bsh[lane];
#pragma unroll
    for (int q = 0; q < 32; q++) o += __shfl(acc, q, 32) * w[q * 32 + lane];
    o = fmaxf(o, 0.f);
    float ss = o * o;
#pragma unroll
    for (int m = 16; m >= 1; m >>= 1) ss += __shfl_xor(ss, m, 32);
    h1[node * 32 + lane] = o / fmaxf(sqrtf(ss), EPSV);
}

// ---- conv2: wave per node; 8-lane group per edge; float4 row gather ----
__global__ __launch_bounds__(256) void conv2_gather_kernel(
        const float* __restrict__ h1, const int* __restrict__ srcS,
        const float2* __restrict__ kS, const int* __restrict__ off,
        float* __restrict__ h2, int N) {
    int wid = threadIdx.x >> 6;
    int lane = threadIdx.x & 63;
    int node = blockIdx.x * 4 + wid;
    if (node >= N) return;

    int grp = lane >> 3;              // 0..7: edge index mod 8
    int cq = lane & 7;                // channel quad: ch = cq*4..cq*4+3
    int start = off[node];
    int deg = off[node + 1] - start;

    float a00 = 0.f, a01 = 0.f, a02 = 0.f, a03 = 0.f;   // k0 * row[cq*4..]
    float a10 = 0.f, a11 = 0.f, a12 = 0.f, a13 = 0.f;   // k1 * row[cq*4..]
    int j = grp;
    for (; j + 8 < deg; j += 16) {    // edges j, j+8
        int p0 = start + j, p1 = start + j + 8;
        int s0 = srcS[p0], s1 = srcS[p1];
        float2 k0 = kS[p0], k1 = kS[p1];
        float4 v0 = *(const float4*)&h1[s0 * 32 + cq * 4];
        float4 v1 = *(const float4*)&h1[s1 * 32 + cq * 4];
        a00 += k0.x * v0.x; a01 += k0.x * v0.y; a02 += k0.x * v0.z; a03 += k0.x * v0.w;
        a10 += k0.y * v0.x; a11 += k0.y * v0.y; a12 += k0.y * v0.z; a13 += k0.y * v0.w;
        a00 += k1.x * v1.x; a01 += k1.x * v1.y; a02 += k1.x * v1.z; a03 += k1.x * v1.w;
        a10 += k1.y * v1.x; a11 += k1.y * v1.y; a12 += k1.y * v1.z; a13 += k1.y * v1.w;
    }
    for (; j < deg; j += 8) {
        int p = start + j;
        int s = srcS[p];
        float2 kk = kS[p];
        float4 v = *(const float4*)&h1[s * 32 + cq * 4];
        a00 += kk.x * v.x; a01 += kk.x * v.y; a02 += kk.x * v.z; a03 += kk.x * v.w;
        a10 += kk.y * v.x; a11 += kk.y * v.y; a12 += kk.y * v.z; a13 += kk.y * v.w;
    }

#pragma unroll
    for (int m = 8; m < 64; m <<= 1) {
        a00 += __shfl_xor(a00, m, 64); a01 += __shfl_xor(a01, m, 64);
        a02 += __shfl_xor(a02, m, 64); a03 += __shfl_xor(a03, m, 64);
        a10 += __shfl_xor(a10, m, 64); a11 += __shfl_xor(a11, m, 64);
        a12 += __shfl_xor(a12, m, 64); a13 += __shfl_xor(a13, m, 64);
    }
    if (grp == 0) {
        float4 o = make_float4(a00, a01, a02, a03);
        *(float4*)&h2[(size_t)node * 64 + cq * 4] = o;
    } else if (grp == 1) {
        float4 o = make_float4(a10, a11, a12, a13);
        *(float4*)&h2[(size_t)node * 64 + 32 + cq * 4] = o;
    }
}

// ---- bf16 helpers ----
__device__ __forceinline__ ushort_t f2bf(float f) {
    uint_t u = __float_as_uint(f);
    uint_t r = u + 0x7FFFu + ((u >> 16) & 1u);
    return (ushort_t)(r >> 16);
}
__device__ __forceinline__ bf16x8 ld_frag(const uint4* p) {
    union { uint4 q; bf16x8 v; } u;
    u.q = *p;
    return u.v;
}

// ---- packW: W2a/W2b -> MFMA B-fragment order (bf16, coalesced uint4) ----
// B-frag for 16x16x32: lane l holds B[k=ks*32+(l>>4)*8+i][n=ct*16+(l&15)].
// wpkA entry (ct*2+ks)*64+l ; wpkB entry (ct*4+ks)*64+l.
__global__ __launch_bounds__(256) void packW_kernel(
        const float* __restrict__ W2a, const float* __restrict__ W2b,
        uint4* __restrict__ wpkA, uint4* __restrict__ wpkB) {
    int gid = blockIdx.x * 256 + threadIdx.x;    // 0..2047
    if (gid < 1024) {
        int ct = gid >> 7, ks = (gid >> 6) & 1, l = gid & 63;
        int kb = l >> 4, m = l & 15;
        ushort_t us[8];
#pragma unroll
        for (int i = 0; i < 8; i++)
            us[i] = f2bf(W2a[(size_t)(ks * 32 + kb * 8 + i) * 128 + ct * 16 + m]);
        uint4 q;
        q.x = (uint_t)us[0] | ((uint_t)us[1] << 16);
        q.y = (uint_t)us[2] | ((uint_t)us[3] << 16);
        q.z = (uint_t)us[4] | ((uint_t)us[5] << 16);
        q.w = (uint_t)us[6] | ((uint_t)us[7] << 16);
        wpkA[gid] = q;
    } else {
        int e = gid - 1024;
        int ct = e >> 8, ks = (e >> 6) & 3, l = e & 63;
        int kb = l >> 4, m = l & 15;
        ushort_t us[8];
#pragma unroll
        for (int i = 0; i < 8; i++)
            us[i] = f2bf(W2b[(size_t)(ks * 32 + kb * 8 + i) * 64 + ct * 16 + m]);
        uint4 q;
        q.x = (uint_t)us[0] | ((uint_t)us[1] << 16);
        q.y = (uint_t)us[2] | ((uint_t)us[3] << 16);
        q.z = (uint_t)us[4] | ((uint_t)us[5] << 16);
        q.w = (uint_t)us[6] | ((uint_t)us[7] << 16);
        wpkB[e] = q;
    }
}

// ---- MLP2 via MFMA: 64 nodes/block, 4 waves x 16 nodes each ----
// A layout (16x16x32): lane l -> row l&15, k=(l>>4)*8+i. C/D: col=lane&15,
// row=(lane>>4)*4+reg (m89-verified). H staged bf16 in LDS (stride 136:
// 16B-aligned rows, 2-way banks).
__global__ __launch_bounds__(256) void mlp2_kernel(
        const float* __restrict__ h2, const uint4* __restrict__ wpkA,
        const float* __restrict__ b2a, const uint4* __restrict__ wpkB,
        const float* __restrict__ b2b, float* __restrict__ out, int N) {
    __shared__ ushort_t hs[64 * 136];   // 17.4 KB

    int tid = threadIdx.x;
    int w = tid >> 6;          // wave 0..3 -> 16-node M-tile
    int l = tid & 63;
    int m = l & 15;
    int kb = l >> 4;           // 0..3
    int rowbase = w * 16;
    int n0 = blockIdx.x * 64;
    int anode = n0 + rowbase + m;      // A-side node for this lane
    bool alive = anode < N;

    // A-frags for GEMM1 (K=64 -> 2 steps) from global X
    bf16x8 a1[2];
#pragma unroll
    for (int ks = 0; ks < 2; ks++) {
        float4 xa = make_float4(0.f, 0.f, 0.f, 0.f), xb = xa;
        if (alive) {
            xa = *(const float4*)&h2[(size_t)anode * 64 + ks * 32 + kb * 8];
            xb = *(const float4*)&h2[(size_t)anode * 64 + ks * 32 + kb * 8 + 4];
        }
        bf16x8 a;
        a[0] = (short)f2bf(xa.x); a[1] = (short)f2bf(xa.y);
        a[2] = (short)f2bf(xa.z); a[3] = (short)f2bf(xa.w);
        a[4] = (short)f2bf(xb.x); a[5] = (short)f2bf(xb.y);
        a[6] = (short)f2bf(xb.z); a[7] = (short)f2bf(xb.w);
        a1[ks] = a;
    }

    // GEMM1: 8 col-tiles x (2 MFMA) -> H[16][128] bf16 in LDS
#pragma unroll
    for (int ct = 0; ct < 8; ct++) {
        f32x4 acc = {0.f, 0.f, 0.f, 0.f};
        acc = __builtin_amdgcn_mfma_f32_16x16x32_bf16(
                  a1[0], ld_frag(&wpkA[(ct * 2 + 0) * 64 + l]), acc, 0, 0, 0);
        acc = __builtin_amdgcn_mfma_f32_16x16x32_bf16(
                  a1[1], ld_frag(&wpkA[(ct * 2 + 1) * 64 + l]), acc, 0, 0, 0);
        float bias = b2a[ct * 16 + m];
#pragma unroll
        for (int r = 0; r < 4; r++) {
            float hv = fmaxf(acc[r] + bias, 0.f);
            hs[(rowbase + kb * 4 + r) * 136 + ct * 16 + m] = f2bf(hv);
        }
    }
    __syncthreads();

    // A-frags for GEMM2 (K=128 -> 4 steps) from LDS (16B-aligned b128)
    bf16x8 a2[4];
#pragma unroll
    for (int ks = 0; ks < 4; ks++) {
        union { uint4 q; bf16x8 v; } u;
        u.q = *(const uint4*)&hs[(rowbase + m) * 136 + ks * 32 + kb * 8];
        a2[ks] = u.v;
    }

    // GEMM2: 4 col-tiles x (4 MFMA)
    f32x4 acc2[4];
#pragma unroll
    for (int ct = 0; ct < 4; ct++) {
        f32x4 acc = {0.f, 0.f, 0.f, 0.f};
#pragma unroll
        for (int ks = 0; ks < 4; ks++)
            acc = __builtin_amdgcn_mfma_f32_16x16x32_bf16(
                      a2[ks], ld_frag(&wpkB[(ct * 4 + ks) * 64 + l]), acc, 0, 0, 0);
        float bias = b2b[ct * 16 + m];
#pragma unroll
        for (int r = 0; r < 4; r++) acc2[ct][r] = acc[r] + bias;
    }

    // l2norm: lane holds rows kb*4+r, cols {ct*16+m}. Reduce over the
    // 16-lane group sharing kb (width-16 xor), then scale+store.
#pragma unroll
    for (int r = 0; r < 4; r++) {
        float ss = acc2[0][r] * acc2[0][r] + acc2[1][r] * acc2[1][r] +
                   acc2[2][r] * acc2[2][r] + acc2[3][r] * acc2[3][r];
        ss += __shfl_xor(ss, 1, 16);
        ss += __shfl_xor(ss, 2, 16);
        ss += __shfl_xor(ss, 4, 16);
        ss += __shfl_xor(ss, 8, 16);
        float invn = 1.0f / fmaxf(sqrtf(ss), EPSV);
        int nrow = n0 + rowbase + kb * 4 + r;
        if (nrow < N) {
#pragma unroll
            for (int ct = 0; ct < 4; ct++)
                out[(size_t)nrow * 64 + ct * 16 + m] = acc2[ct][r] * invn;
        }
    }
}

extern "C" void kernel_launch(void* const* d_in, const int* in_sizes, int n_in,
                              void* d_out, int out_size, void* d_ws, size_t ws_size,
                              hipStream_t stream) {
    const float* x   = (const float*)d_in[0];
    const float* K   = (const float*)d_in[1];
    const int*   ei  = (const int*)d_in[2];
    const float* W1  = (const float*)d_in[3];
    const float* b1  = (const float*)d_in[4];
    const float* W2a = (const float*)d_in[5];
    const float* b2a = (const float*)d_in[6];
    const float* W2b = (const float*)d_in[7];
    const float* b2b = (const float*)d_in[8];
    float* out = (float*)d_out;

    const int D  = 16;
    const int NK = 2;
    const int N  = in_sizes[0] / D;        // 50000
    const int E  = in_sizes[1] / NK;       // 1600000
    const int nbuck = (N + BNODES - 1) >> BSH;  // 391 <= NB2
    const int HROWS = 256;                 // bhist blocks

    // workspace layout:
    //   region0 (overlaid in time):
    //     phase 1 (CSR build): staging int4[E]      (E*16 bytes)
    //     phase 2+3:           h2[N*64] | h1[N*32]  (N*384 bytes)
    //   then: srcS[E] | kS[E] (float2) | off[N+1] | cntmat[HROWS*NB2] |
    //         bbase[NB2+1] | bcur[NB2*BCPAD] | flag[1] | wpkA[1024] | wpkB[1024]
    size_t region0 = (size_t)E * 16;
    size_t hbytes  = (size_t)N * 96 * 4;
    if (hbytes > region0) region0 = hbytes;

    float* h2       = (float*)d_ws;
    float* h1       = h2 + (size_t)N * 64;
    int4* staging   = (int4*)d_ws;
    int* srcS       = (int*)((char*)d_ws + region0);
    float2* kS      = (float2*)(srcS + (size_t)E);
    int* off        = (int*)(kS + (size_t)E);
    int* cntmat     = off + (N + 1);
    int* bbase      = cntmat + HROWS * NB2;
    int* bcur       = bbase + NB2 + 1;
    int* flag       = bcur + NB2 * BCPAD;
    char* wp        = (char*)(flag + 1);
    wp = (char*)(((size_t)wp + 15) & ~(size_t)15);
    uint4* wpkA     = (uint4*)wp;
    uint4* wpkB     = wpkA + 1024;

    detect_i64_kernel<<<1, 64, 0, stream>>>(ei, flag);
    packW_kernel<<<8, 256, 0, stream>>>(W2a, W2b, wpkA, wpkB);
    bhist_kernel<<<HROWS, 256, 0, stream>>>(ei, flag, cntmat, E);
    bscan_kernel<<<1, NB2, 0, stream>>>(cntmat, bbase, bcur, off,
                                        nbuck, E, HROWS, N);

    int ablocks = (E + CHUNK - 1) / CHUNK;
    partA_kernel<<<ablocks, 256, 0, stream>>>(K, ei, flag, bcur, staging, E);
    partB_kernel<<<nbuck, 256, 0, stream>>>(staging, bbase, off, srcS, kS, N);

    conv1_mlp1_kernel<<<(N + 7) / 8, 256, 0, stream>>>(x, srcS, kS, off,
                                                       W1, b1, h1, N);
    conv2_gather_kernel<<<(N + 3) / 4, 256, 0, stream>>>(h1, srcS, kS, off,
                                                         h2, N);
    mlp2_kernel<<<(N + 63) / 64, 256, 0, stream>>>(h2, wpkA, b2a, wpkB, b2b,
                                                   out, N);
}